// Round 1
// baseline (1862.271 us; speedup 1.0000x reference)
//
#include <hip/hip_runtime.h>
#include <hip/hip_bf16.h>
#include <stdint.h>

// Problem constants
constexpr int Bn = 8;              // batches
constexpr int Np = 8192;           // points per batch
constexpr int Gc = 512;            // FPS centers / groups
constexpr int Kn = 32;             // knn neighbors
constexpr int Mrows = Bn * Gc * Kn;  // 131072 encoder rows
constexpr float LNEPS = 1e-5f;

using f32x4  = __attribute__((ext_vector_type(4))) float;
using bf16x8 = __attribute__((ext_vector_type(8))) __bf16;

#define DEVINL __device__ __forceinline__

// ---------------------------------------------------------------------------
// FPS: one block per batch, 1024 threads, 8 points/thread in registers.
// Must match reference arithmetic exactly: d = ((dx*dx)+(dy*dy))+(dz*dz) in f32,
// argmax tie -> smallest index (numpy first-occurrence).
// ---------------------------------------------------------------------------
__global__ __launch_bounds__(1024) void fps_kernel(const float* __restrict__ xyz,
                                                   float* __restrict__ centers)
{
    const int b = blockIdx.x;
    const int t = threadIdx.x;
    __shared__ float xs[Np], ys[Np], zs[Np];
    __shared__ float rv[16];
    __shared__ int   ri[16];
    __shared__ int   swin;
    const float* P = xyz + (size_t)b * Np * 3;
    float rx[8], ry[8], rz[8], md[8];
#pragma unroll
    for (int i = 0; i < 8; ++i) {
        int p = i * 1024 + t;
        rx[i] = P[p * 3 + 0];
        ry[i] = P[p * 3 + 1];
        rz[i] = P[p * 3 + 2];
        xs[p] = rx[i]; ys[p] = ry[i]; zs[p] = rz[i];
        md[i] = __builtin_inff();
    }
    if (t == 0) {
        centers[(size_t)(b * Gc) * 3 + 0] = P[0];
        centers[(size_t)(b * Gc) * 3 + 1] = P[1];
        centers[(size_t)(b * Gc) * 3 + 2] = P[2];
    }
    __syncthreads();
    int last = 0;
    for (int g = 1; g < Gc; ++g) {
        float lx = xs[last], ly = ys[last], lz = zs[last];
        float bv = -__builtin_inff();
        int   bi = 0x7fffffff;
#pragma unroll
        for (int i = 0; i < 8; ++i) {
            float dx = __fsub_rn(rx[i], lx);
            float dy = __fsub_rn(ry[i], ly);
            float dz = __fsub_rn(rz[i], lz);
            float d  = __fadd_rn(__fadd_rn(__fmul_rn(dx, dx), __fmul_rn(dy, dy)), __fmul_rn(dz, dz));
            md[i] = fminf(md[i], d);
            if (md[i] > bv) { bv = md[i]; bi = i * 1024 + t; }
        }
#pragma unroll
        for (int m = 1; m < 64; m <<= 1) {
            float ov = __shfl_xor(bv, m, 64);
            int   oi = __shfl_xor(bi, m, 64);
            if (ov > bv || (ov == bv && oi < bi)) { bv = ov; bi = oi; }
        }
        if ((t & 63) == 0) { rv[t >> 6] = bv; ri[t >> 6] = bi; }
        __syncthreads();
        if (t == 0) {
            float wv = rv[0]; int wi = ri[0];
            for (int w = 1; w < 16; ++w)
                if (rv[w] > wv || (rv[w] == wv && ri[w] < wi)) { wv = rv[w]; wi = ri[w]; }
            swin = wi;
            centers[(size_t)(b * Gc + g) * 3 + 0] = xs[wi];
            centers[(size_t)(b * Gc + g) * 3 + 1] = ys[wi];
            centers[(size_t)(b * Gc + g) * 3 + 2] = zs[wi];
        }
        __syncthreads();
        last = swin;
    }
}

// ---------------------------------------------------------------------------
// KNN + gather + feature build: one block (256 thr) per (b,g).
// d = -2*dot + |c|^2 + |p|^2 exactly as reference; 32x min-extraction,
// tie -> smallest index (stable top_k). Exclusion via per-thread bitmask
// (no runtime-indexed register arrays -> no scratch).
// ---------------------------------------------------------------------------
__global__ __launch_bounds__(256) void knn_feats_kernel(const float* __restrict__ xyz,
                                                        const float* __restrict__ color,
                                                        const float* __restrict__ centers,
                                                        float* __restrict__ feats)
{
    const int bg = blockIdx.x;
    const int b  = bg >> 9;
    const int t  = threadIdx.x;
    __shared__ float rv[4];
    __shared__ int   ri[4], swin, sel[Kn];
    const float cx = centers[(size_t)bg * 3 + 0];
    const float cy = centers[(size_t)bg * 3 + 1];
    const float cz = centers[(size_t)bg * 3 + 2];
    const float cc = __fadd_rn(__fadd_rn(__fmul_rn(cx, cx), __fmul_rn(cy, cy)), __fmul_rn(cz, cz));
    const float* P = xyz + (size_t)b * Np * 3;
    float dr[32];
#pragma unroll
    for (int i = 0; i < 32; ++i) {
        int p = i * 256 + t;
        float px = P[p * 3 + 0], py = P[p * 3 + 1], pz = P[p * 3 + 2];
        float dot = __fadd_rn(__fadd_rn(__fmul_rn(cx, px), __fmul_rn(cy, py)), __fmul_rn(cz, pz));
        float pp  = __fadd_rn(__fadd_rn(__fmul_rn(px, px), __fmul_rn(py, py)), __fmul_rn(pz, pz));
        dr[i] = __fadd_rn(__fadd_rn(__fmul_rn(-2.0f, dot), cc), pp);
    }
    const int lane = t & 63, wvi = t >> 6;
    unsigned excl = 0;
    for (int k = 0; k < Kn; ++k) {
        float bd = __builtin_inff();
        int   bi = 0x7fffffff;
#pragma unroll
        for (int i = 0; i < 32; ++i) {
            float d  = ((excl >> i) & 1u) ? __builtin_inff() : dr[i];
            int  idx = i * 256 + t;
            if (d < bd || (d == bd && idx < bi)) { bd = d; bi = idx; }
        }
#pragma unroll
        for (int m = 1; m < 64; m <<= 1) {
            float od = __shfl_xor(bd, m, 64);
            int   oi = __shfl_xor(bi, m, 64);
            if (od < bd || (od == bd && oi < bi)) { bd = od; bi = oi; }
        }
        if (lane == 0) { rv[wvi] = bd; ri[wvi] = bi; }
        __syncthreads();
        if (t == 0) {
            float wd = rv[0]; int wi = ri[0];
            for (int w = 1; w < 4; ++w)
                if (rv[w] < wd || (rv[w] == wd && ri[w] < wi)) { wd = rv[w]; wi = ri[w]; }
            sel[k] = wi; swin = wi;
        }
        __syncthreads();
        int wi = swin;
        if ((wi & 255) == t) excl |= 1u << (wi >> 8);
    }
    __syncthreads();
    if (t < Kn) {
        int wi = sel[t];
        float px = P[wi * 3 + 0], py = P[wi * 3 + 1], pz = P[wi * 3 + 2];
        const float* C = color + (size_t)b * Np * 3;
        float* F = feats + (size_t)(bg * Kn + t) * 6;
        F[0] = px - cx; F[1] = py - cy; F[2] = pz - cz;
        F[3] = C[wi * 3 + 0]; F[4] = C[wi * 3 + 1]; F[5] = C[wi * 3 + 2];
    }
}

// ---------------------------------------------------------------------------
// Weight cast f32 -> bf16 (w2, w3, w4)
// ---------------------------------------------------------------------------
__global__ void cast_w_kernel(const float* __restrict__ w2, const float* __restrict__ w3,
                              const float* __restrict__ w4,
                              __hip_bfloat16* __restrict__ o2, __hip_bfloat16* __restrict__ o3,
                              __hip_bfloat16* __restrict__ o4)
{
    int i = blockIdx.x * 256 + threadIdx.x;   // grid covers 262144
    if (i < 256 * 128) o2[i] = __float2bfloat16(w2[i]);
    o3[i] = __float2bfloat16(w3[i]);
    o4[i] = __float2bfloat16(w4[i]);
}

// ---------------------------------------------------------------------------
// h1 = relu(LN(feats @ w1^T + b1)); one wave per row (64 lanes x 2 channels)
// ---------------------------------------------------------------------------
__global__ __launch_bounds__(256) void h1_kernel(const float* __restrict__ feats,
                                                 const float* __restrict__ w1,
                                                 const float* __restrict__ b1,
                                                 const float* __restrict__ g1,
                                                 const float* __restrict__ be1,
                                                 __hip_bfloat16* __restrict__ h1)
{
    const int gtid = blockIdx.x * 256 + threadIdx.x;
    const int row  = gtid >> 6;
    const int lane = gtid & 63;
    const float* f = feats + (size_t)row * 6;
    float fr[6];
#pragma unroll
    for (int i = 0; i < 6; ++i) fr[i] = f[i];
    const int c0 = lane * 2;
    float a0 = b1[c0], a1 = b1[c0 + 1];
#pragma unroll
    for (int i = 0; i < 6; ++i) {
        a0 = fmaf(w1[c0 * 6 + i], fr[i], a0);
        a1 = fmaf(w1[(c0 + 1) * 6 + i], fr[i], a1);
    }
    float s = a0 + a1;
#pragma unroll
    for (int m = 1; m < 64; m <<= 1) s += __shfl_xor(s, m, 64);
    float mu = s * (1.f / 128.f);
    float d0 = a0 - mu, d1 = a1 - mu;
    float q = d0 * d0 + d1 * d1;
#pragma unroll
    for (int m = 1; m < 64; m <<= 1) q += __shfl_xor(q, m, 64);
    float iv = rsqrtf(q * (1.f / 128.f) + LNEPS);
    float y0 = fmaxf(0.f, d0 * iv * g1[c0] + be1[c0]);
    float y1 = fmaxf(0.f, d1 * iv * g1[c0 + 1] + be1[c0 + 1]);
    __hip_bfloat16* dst = h1 + (size_t)row * 128 + c0;
    dst[0] = __float2bfloat16(y0);
    dst[1] = __float2bfloat16(y1);
}

// ---------------------------------------------------------------------------
// hg: per-group column max over h2 (x3 cols [256,512)) broadcast into cols [0,256)
// ---------------------------------------------------------------------------
__global__ __launch_bounds__(256) void hgmax_kernel(__hip_bfloat16* x3)
{
    const int grp = blockIdx.x;
    const int t   = threadIdx.x;
    const size_t base = (size_t)grp * 32 * 512;
    float m = -__builtin_inff();
#pragma unroll 4
    for (int r = 0; r < 32; ++r)
        m = fmaxf(m, __bfloat162float(x3[base + (size_t)r * 512 + 256 + t]));
    __hip_bfloat16 mb = __float2bfloat16(m);
#pragma unroll 4
    for (int r = 0; r < 32; ++r)
        x3[base + (size_t)r * 512 + t] = mb;
}

// ---------------------------------------------------------------------------
// GEMM: C[m,n] = sum_k A[m,k] * W[n,k]  (+ epilogues)
// BM=128, BN=256/512 (full N per block), BK=64, 8 waves (2Mx4N), wave tile 64xWN.
// Staged via global_load_lds(16B) into XOR-swizzled ((row&7)<<4) LDS, dbuf.
// EPI 0: +bias, store bf16 at col offset ocol0 (ld 512)    [h2 -> x3 high half]
// EPI 1: +bias, LayerNorm(BN) * gamma + beta, ReLU, bf16   [h3 -> x3 in-place]
// EPI 2: +bias, max over 32-row groups, store f32          [h4 -> out]
// ---------------------------------------------------------------------------
template <int BN, int EPI>
__global__ __launch_bounds__(512, 2) void gemm_kernel(
    const __hip_bfloat16* A, int lda,
    const __hip_bfloat16* __restrict__ Bw, int ldb, int nkt,
    const float* __restrict__ bias,
    const float* __restrict__ gamma, const float* __restrict__ beta,
    __hip_bfloat16* outB, int ocol0,
    float* __restrict__ outF)
{
    constexpr int BM = 128, BK = 64;
    constexpr int WN = BN / 4;
    constexpr int NI = WN / 16;
    constexpr int MI = 4;
    constexpr int A_ELE = BM * BK;
    constexpr int B_ELE = BN * BK;
    constexpr int BUF = A_ELE + B_ELE;
    constexpr int ACH = A_ELE * 2 / 16 / 512;   // 16B chunks per thread for A
    constexpr int BCH = B_ELE * 2 / 16 / 512;
    __shared__ __hip_bfloat16 smem[2 * BUF];

    const int tid  = threadIdx.x;
    const int wid  = tid >> 6, lane = tid & 63;
    const int wm   = wid >> 2, wn = wid & 3;
    const int lrow = lane & 15, lq = lane >> 4;
    const int m0   = blockIdx.x * BM;

    f32x4 acc[MI][NI] = {};

    auto stage = [&](int buf, int k0) {
        const char* Ab = (const char*)A + ((size_t)m0 * lda + k0) * 2;
        const char* Bb = (const char*)Bw + (size_t)k0 * 2;
        char* sA = (char*)(smem + (size_t)buf * BUF);
        char* sB = sA + A_ELE * 2;
#pragma unroll
        for (int i = 0; i < ACH; ++i) {
            int chunk = i * 512 + tid;
            int Pp = chunk * 16;
            int row = Pp >> 7;
            int kb = (Pp & 127) ^ ((row & 7) << 4);
            const void* g = Ab + (size_t)row * (lda * 2) + kb;
            void* l = sA + (i * 512 + wid * 64) * 16;
            __builtin_amdgcn_global_load_lds((const __attribute__((address_space(1))) void*)g,
                                             (__attribute__((address_space(3))) void*)l, 16, 0, 0);
        }
#pragma unroll
        for (int i = 0; i < BCH; ++i) {
            int chunk = i * 512 + tid;
            int Pp = chunk * 16;
            int n = Pp >> 7;
            int kb = (Pp & 127) ^ ((n & 7) << 4);
            const void* g = Bb + (size_t)n * (ldb * 2) + kb;
            void* l = sB + (i * 512 + wid * 64) * 16;
            __builtin_amdgcn_global_load_lds((const __attribute__((address_space(1))) void*)g,
                                             (__attribute__((address_space(3))) void*)l, 16, 0, 0);
        }
    };

    auto compute = [&](int buf) {
        const char* sA = (const char*)(smem + (size_t)buf * BUF);
        const char* sB = sA + A_ELE * 2;
#pragma unroll
        for (int kk = 0; kk < 2; ++kk) {
            bf16x8 af[MI], bfv[NI];
#pragma unroll
            for (int mi = 0; mi < MI; ++mi) {
                int row = wm * 64 + mi * 16 + lrow;
                int off = row * 128 + ((kk * 64 + lq * 16) ^ ((row & 7) << 4));
                af[mi] = *(const bf16x8*)(sA + off);
            }
#pragma unroll
            for (int ni = 0; ni < NI; ++ni) {
                int n = wn * WN + ni * 16 + lrow;
                int off = n * 128 + ((kk * 64 + lq * 16) ^ ((n & 7) << 4));
                bfv[ni] = *(const bf16x8*)(sB + off);
            }
#pragma unroll
            for (int mi = 0; mi < MI; ++mi)
#pragma unroll
                for (int ni = 0; ni < NI; ++ni)
                    acc[mi][ni] = __builtin_amdgcn_mfma_f32_16x16x32_bf16(af[mi], bfv[ni], acc[mi][ni], 0, 0, 0);
        }
    };

    stage(0, 0);
    __syncthreads();
    int cur = 0;
    for (int kt = 0; kt < nkt; ++kt) {
        if (kt + 1 < nkt) stage(cur ^ 1, (kt + 1) * BK);
        compute(cur);
        __syncthreads();
        cur ^= 1;
    }

    float bv[NI];
#pragma unroll
    for (int ni = 0; ni < NI; ++ni) bv[ni] = bias[wn * WN + ni * 16 + lrow];

    if constexpr (EPI == 0) {
#pragma unroll
        for (int mi = 0; mi < MI; ++mi)
#pragma unroll
            for (int ni = 0; ni < NI; ++ni) {
                int col = ocol0 + wn * WN + ni * 16 + lrow;
#pragma unroll
                for (int j = 0; j < 4; ++j) {
                    int row = wm * 64 + mi * 16 + lq * 4 + j;
                    outB[(size_t)(m0 + row) * 512 + col] = __float2bfloat16(acc[mi][ni][j] + bv[ni]);
                }
            }
    } else if constexpr (EPI == 1) {
        float gv[NI], bev[NI];
#pragma unroll
        for (int ni = 0; ni < NI; ++ni) {
            int col = wn * WN + ni * 16 + lrow;
            gv[ni] = gamma[col]; bev[ni] = beta[col];
        }
#pragma unroll
        for (int mi = 0; mi < MI; ++mi)
#pragma unroll
            for (int ni = 0; ni < NI; ++ni)
#pragma unroll
                for (int j = 0; j < 4; ++j) acc[mi][ni][j] += bv[ni];

        float* rs  = (float*)smem;        // [BM][4] row partial sums
        float* rq  = rs + BM * 4;
        float* rmu = rq + BM * 4;
        float* riv = rmu + BM;
#pragma unroll
        for (int mi = 0; mi < MI; ++mi) {
#pragma unroll
            for (int j = 0; j < 4; ++j) {
                float s = 0.f, q = 0.f;
#pragma unroll
                for (int ni = 0; ni < NI; ++ni) { float v = acc[mi][ni][j]; s += v; q += v * v; }
#pragma unroll
                for (int m = 1; m < 16; m <<= 1) { s += __shfl_xor(s, m, 64); q += __shfl_xor(q, m, 64); }
                if (lrow == 0) {
                    int row = wm * 64 + mi * 16 + lq * 4 + j;
                    rs[row * 4 + wn] = s;
                    rq[row * 4 + wn] = q;
                }
            }
        }
        __syncthreads();
        if (tid < BM) {
            float S = rs[tid * 4 + 0] + rs[tid * 4 + 1] + rs[tid * 4 + 2] + rs[tid * 4 + 3];
            float Q = rq[tid * 4 + 0] + rq[tid * 4 + 1] + rq[tid * 4 + 2] + rq[tid * 4 + 3];
            float mu = S * (1.f / BN);
            float var = Q * (1.f / BN) - mu * mu;
            rmu[tid] = mu;
            riv[tid] = rsqrtf(var + LNEPS);
        }
        __syncthreads();
#pragma unroll
        for (int mi = 0; mi < MI; ++mi)
#pragma unroll
            for (int j = 0; j < 4; ++j) {
                int row = wm * 64 + mi * 16 + lq * 4 + j;
                float mu = rmu[row], iv = riv[row];
#pragma unroll
                for (int ni = 0; ni < NI; ++ni) {
                    float v = (acc[mi][ni][j] - mu) * iv * gv[ni] + bev[ni];
                    v = fmaxf(v, 0.f);
                    outB[(size_t)(m0 + row) * 512 + (wn * WN + ni * 16 + lrow)] = __float2bfloat16(v);
                }
            }
    } else {
#pragma unroll
        for (int grp = 0; grp < 2; ++grp) {
            float mx[NI];
#pragma unroll
            for (int ni = 0; ni < NI; ++ni) {
                float m = -__builtin_inff();
#pragma unroll
                for (int mh = 0; mh < 2; ++mh) {
                    int mi = grp * 2 + mh;
#pragma unroll
                    for (int j = 0; j < 4; ++j) m = fmaxf(m, acc[mi][ni][j] + bv[ni]);
                }
                mx[ni] = m;
            }
#pragma unroll
            for (int ni = 0; ni < NI; ++ni) {
                mx[ni] = fmaxf(mx[ni], __shfl_xor(mx[ni], 16, 64));
                mx[ni] = fmaxf(mx[ni], __shfl_xor(mx[ni], 32, 64));
            }
            if (lq == 0) {
                int grow = (m0 >> 5) + wm * 2 + grp;
#pragma unroll
                for (int ni = 0; ni < NI; ++ni)
                    outF[(size_t)grow * 512 + wn * WN + ni * 16 + lrow] = mx[ni];
            }
        }
    }
}

// ---------------------------------------------------------------------------
extern "C" void kernel_launch(void* const* d_in, const int* in_sizes, int n_in,
                              void* d_out, int out_size, void* d_ws, size_t ws_size,
                              hipStream_t stream)
{
    const float* xyz   = (const float*)d_in[0];
    const float* color = (const float*)d_in[1];
    const float* w1  = (const float*)d_in[2];
    const float* b1  = (const float*)d_in[3];
    const float* g1  = (const float*)d_in[4];
    const float* be1 = (const float*)d_in[5];
    const float* w2  = (const float*)d_in[6];
    const float* b2  = (const float*)d_in[7];
    const float* w3  = (const float*)d_in[8];
    const float* b3  = (const float*)d_in[9];
    const float* g2  = (const float*)d_in[10];
    const float* be2 = (const float*)d_in[11];
    const float* w4  = (const float*)d_in[12];
    const float* b4  = (const float*)d_in[13];
    float* out = (float*)d_out;

    char* ws = (char*)d_ws;
    size_t off = 0;
    auto alloc = [&](size_t bytes) -> void* {
        void* p = ws + off;
        off += (bytes + 255) & ~(size_t)255;
        return p;
    };
    float* centers      = (float*)alloc((size_t)Bn * Gc * 3 * 4);
    float* feats        = (float*)alloc((size_t)Mrows * 6 * 4);
    __hip_bfloat16* w2b = (__hip_bfloat16*)alloc((size_t)256 * 128 * 2);
    __hip_bfloat16* w3b = (__hip_bfloat16*)alloc((size_t)512 * 512 * 2);
    __hip_bfloat16* w4b = (__hip_bfloat16*)alloc((size_t)512 * 512 * 2);
    __hip_bfloat16* h1b = (__hip_bfloat16*)alloc((size_t)Mrows * 128 * 2);
    __hip_bfloat16* x3  = (__hip_bfloat16*)alloc((size_t)Mrows * 512 * 2);
    (void)ws_size; (void)in_sizes; (void)n_in; (void)out_size;

    fps_kernel<<<Bn, 1024, 0, stream>>>(xyz, centers);
    knn_feats_kernel<<<Bn * Gc, 256, 0, stream>>>(xyz, color, centers, feats);
    cast_w_kernel<<<1024, 256, 0, stream>>>(w2, w3, w4, w2b, w3b, w4b);
    h1_kernel<<<Mrows / 4, 256, 0, stream>>>(feats, w1, b1, g1, be1, h1b);
    gemm_kernel<256, 0><<<Mrows / 128, 512, 0, stream>>>(h1b, 128, w2b, 128, 2,  b2, nullptr, nullptr, x3, 256, nullptr);
    hgmax_kernel<<<Bn * Gc, 256, 0, stream>>>(x3);
    gemm_kernel<512, 1><<<Mrows / 128, 512, 0, stream>>>(x3, 512, w3b, 512, 8,  b3, g2, be2, x3, 0, nullptr);
    gemm_kernel<512, 2><<<Mrows / 128, 512, 0, stream>>>(x3, 512, w4b, 512, 8,  b4, nullptr, nullptr, nullptr, 0, out);
}

// Round 2
// 1136.267 us; speedup vs baseline: 1.6389x; 1.6389x over previous
//
#include <hip/hip_runtime.h>
#include <hip/hip_bf16.h>
#include <stdint.h>

// Problem constants
constexpr int Bn = 8;              // batches
constexpr int Np = 8192;           // points per batch
constexpr int Gc = 512;            // FPS centers / groups
constexpr int Kn = 32;             // knn neighbors
constexpr int Mrows = Bn * Gc * Kn;  // 131072 encoder rows
constexpr float LNEPS = 1e-5f;

using f32x4  = __attribute__((ext_vector_type(4))) float;
using bf16x8 = __attribute__((ext_vector_type(8))) __bf16;

// ---------------------------------------------------------------------------
// FPS v2: one block per batch, 512 threads (8 waves), 16 points/thread.
// Exact reference arithmetic: d = ((dx*dx)+(dy*dy))+(dz*dz) in f32 (rn),
// argmax tie -> smallest index.
// (dist,idx) packed in u64: hi = float bits of md (md>=0 so monotonic),
// lo = ~idx (so u64-max => max dist, tie => smallest idx).
// ONE barrier per iteration: per-wave winners in double-buffered LDS slots;
// after the barrier every wave reduces the 8 slots itself (broadcast reads).
// ---------------------------------------------------------------------------
__global__ __launch_bounds__(512) void fps_kernel(const float* __restrict__ xyz,
                                                  float* __restrict__ centers)
{
    const int b = blockIdx.x;
    const int t = threadIdx.x;
    __shared__ float xs[Np], ys[Np], zs[Np];
    __shared__ unsigned long long red[2][8];
    const float* P = xyz + (size_t)b * Np * 3;
    float rx[16], ry[16], rz[16], md[16];
#pragma unroll
    for (int i = 0; i < 16; ++i) {
        int p = i * 512 + t;
        rx[i] = P[p * 3 + 0];
        ry[i] = P[p * 3 + 1];
        rz[i] = P[p * 3 + 2];
        xs[p] = rx[i]; ys[p] = ry[i]; zs[p] = rz[i];
        md[i] = __builtin_inff();
    }
    if (t == 0) {
        centers[(size_t)(b * Gc) * 3 + 0] = P[0];
        centers[(size_t)(b * Gc) * 3 + 1] = P[1];
        centers[(size_t)(b * Gc) * 3 + 2] = P[2];
    }
    __syncthreads();
    int last = 0;
    const int wv = t >> 6, lane = t & 63;
    const unsigned nt = ~(unsigned)t;
    for (int g = 1; g < Gc; ++g) {
        float lx = xs[last], ly = ys[last], lz = zs[last];
        unsigned long long best = 0ull;
#pragma unroll
        for (int i = 0; i < 16; ++i) {
            float dx = __fsub_rn(rx[i], lx);
            float dy = __fsub_rn(ry[i], ly);
            float dz = __fsub_rn(rz[i], lz);
            float d  = __fadd_rn(__fadd_rn(__fmul_rn(dx, dx), __fmul_rn(dy, dy)), __fmul_rn(dz, dz));
            md[i] = fminf(md[i], d);
            // lo = ~(i*512+t) = ~t - i*512
            unsigned long long cand =
                ((unsigned long long)__float_as_uint(md[i]) << 32) | (unsigned long long)(nt - (unsigned)(i * 512));
            best = cand > best ? cand : best;
        }
#pragma unroll
        for (int m = 1; m < 64; m <<= 1) {
            unsigned long long o = __shfl_xor(best, m, 64);
            best = o > best ? o : best;
        }
        if (lane == 0) red[g & 1][wv] = best;
        __syncthreads();
        unsigned long long w0 = red[g & 1][0];
#pragma unroll
        for (int w = 1; w < 8; ++w) {
            unsigned long long o = red[g & 1][w];
            w0 = o > w0 ? o : w0;
        }
        int wi = (int)(~(unsigned)w0);
        if (t == 0) {
            centers[(size_t)(b * Gc + g) * 3 + 0] = xs[wi];
            centers[(size_t)(b * Gc + g) * 3 + 1] = ys[wi];
            centers[(size_t)(b * Gc + g) * 3 + 2] = zs[wi];
        }
        last = wi;
    }
}

// ---------------------------------------------------------------------------
// KNN + gather + feature build: one block (256 thr) per (b,g).
// d = -2*dot + |c|^2 + |p|^2 exactly as reference; 32x min-extraction,
// tie -> smallest index (stable top_k).
// ---------------------------------------------------------------------------
__global__ __launch_bounds__(256) void knn_feats_kernel(const float* __restrict__ xyz,
                                                        const float* __restrict__ color,
                                                        const float* __restrict__ centers,
                                                        float* __restrict__ feats)
{
    const int bg = blockIdx.x;
    const int b  = bg >> 9;
    const int t  = threadIdx.x;
    __shared__ float rv[4];
    __shared__ int   ri[4], swin, sel[Kn];
    const float cx = centers[(size_t)bg * 3 + 0];
    const float cy = centers[(size_t)bg * 3 + 1];
    const float cz = centers[(size_t)bg * 3 + 2];
    const float cc = __fadd_rn(__fadd_rn(__fmul_rn(cx, cx), __fmul_rn(cy, cy)), __fmul_rn(cz, cz));
    const float* P = xyz + (size_t)b * Np * 3;
    float dr[32];
#pragma unroll
    for (int i = 0; i < 32; ++i) {
        int p = i * 256 + t;
        float px = P[p * 3 + 0], py = P[p * 3 + 1], pz = P[p * 3 + 2];
        float dot = __fadd_rn(__fadd_rn(__fmul_rn(cx, px), __fmul_rn(cy, py)), __fmul_rn(cz, pz));
        float pp  = __fadd_rn(__fadd_rn(__fmul_rn(px, px), __fmul_rn(py, py)), __fmul_rn(pz, pz));
        dr[i] = __fadd_rn(__fadd_rn(__fmul_rn(-2.0f, dot), cc), pp);
    }
    const int lane = t & 63, wvi = t >> 6;
    unsigned excl = 0;
    for (int k = 0; k < Kn; ++k) {
        float bd = __builtin_inff();
        int   bi = 0x7fffffff;
#pragma unroll
        for (int i = 0; i < 32; ++i) {
            float d  = ((excl >> i) & 1u) ? __builtin_inff() : dr[i];
            int  idx = i * 256 + t;
            if (d < bd || (d == bd && idx < bi)) { bd = d; bi = idx; }
        }
#pragma unroll
        for (int m = 1; m < 64; m <<= 1) {
            float od = __shfl_xor(bd, m, 64);
            int   oi = __shfl_xor(bi, m, 64);
            if (od < bd || (od == bd && oi < bi)) { bd = od; bi = oi; }
        }
        if (lane == 0) { rv[wvi] = bd; ri[wvi] = bi; }
        __syncthreads();
        if (t == 0) {
            float wd = rv[0]; int wi = ri[0];
            for (int w = 1; w < 4; ++w)
                if (rv[w] < wd || (rv[w] == wd && ri[w] < wi)) { wd = rv[w]; wi = ri[w]; }
            sel[k] = wi; swin = wi;
        }
        __syncthreads();
        int wi = swin;
        if ((wi & 255) == t) excl |= 1u << (wi >> 8);
    }
    __syncthreads();
    if (t < Kn) {
        int wi = sel[t];
        float px = P[wi * 3 + 0], py = P[wi * 3 + 1], pz = P[wi * 3 + 2];
        const float* C = color + (size_t)b * Np * 3;
        float* F = feats + (size_t)(bg * Kn + t) * 6;
        F[0] = px - cx; F[1] = py - cy; F[2] = pz - cz;
        F[3] = C[wi * 3 + 0]; F[4] = C[wi * 3 + 1]; F[5] = C[wi * 3 + 2];
    }
}

// ---------------------------------------------------------------------------
// Weight cast f32 -> bf16 (w2, w3, w4)
// ---------------------------------------------------------------------------
__global__ void cast_w_kernel(const float* __restrict__ w2, const float* __restrict__ w3,
                              const float* __restrict__ w4,
                              __hip_bfloat16* __restrict__ o2, __hip_bfloat16* __restrict__ o3,
                              __hip_bfloat16* __restrict__ o4)
{
    int i = blockIdx.x * 256 + threadIdx.x;   // grid covers 262144
    if (i < 256 * 128) o2[i] = __float2bfloat16(w2[i]);
    o3[i] = __float2bfloat16(w3[i]);
    o4[i] = __float2bfloat16(w4[i]);
}

// ---------------------------------------------------------------------------
// h1 = relu(LN(feats @ w1^T + b1)); one wave per row (64 lanes x 2 channels)
// ---------------------------------------------------------------------------
__global__ __launch_bounds__(256) void h1_kernel(const float* __restrict__ feats,
                                                 const float* __restrict__ w1,
                                                 const float* __restrict__ b1,
                                                 const float* __restrict__ g1,
                                                 const float* __restrict__ be1,
                                                 __hip_bfloat16* __restrict__ h1)
{
    const int gtid = blockIdx.x * 256 + threadIdx.x;
    const int row  = gtid >> 6;
    const int lane = gtid & 63;
    const float* f = feats + (size_t)row * 6;
    float fr[6];
#pragma unroll
    for (int i = 0; i < 6; ++i) fr[i] = f[i];
    const int c0 = lane * 2;
    float a0 = b1[c0], a1 = b1[c0 + 1];
#pragma unroll
    for (int i = 0; i < 6; ++i) {
        a0 = fmaf(w1[c0 * 6 + i], fr[i], a0);
        a1 = fmaf(w1[(c0 + 1) * 6 + i], fr[i], a1);
    }
    float s = a0 + a1;
#pragma unroll
    for (int m = 1; m < 64; m <<= 1) s += __shfl_xor(s, m, 64);
    float mu = s * (1.f / 128.f);
    float d0 = a0 - mu, d1 = a1 - mu;
    float q = d0 * d0 + d1 * d1;
#pragma unroll
    for (int m = 1; m < 64; m <<= 1) q += __shfl_xor(q, m, 64);
    float iv = rsqrtf(q * (1.f / 128.f) + LNEPS);
    float y0 = fmaxf(0.f, d0 * iv * g1[c0] + be1[c0]);
    float y1 = fmaxf(0.f, d1 * iv * g1[c0 + 1] + be1[c0 + 1]);
    __hip_bfloat16* dst = h1 + (size_t)row * 128 + c0;
    dst[0] = __float2bfloat16(y0);
    dst[1] = __float2bfloat16(y1);
}

// ---------------------------------------------------------------------------
// hg: per-group column max over h2 (x3 cols [256,512)) broadcast into cols [0,256)
// ---------------------------------------------------------------------------
__global__ __launch_bounds__(256) void hgmax_kernel(__hip_bfloat16* x3)
{
    const int grp = blockIdx.x;
    const int t   = threadIdx.x;
    const size_t base = (size_t)grp * 32 * 512;
    float m = -__builtin_inff();
#pragma unroll 4
    for (int r = 0; r < 32; ++r)
        m = fmaxf(m, __bfloat162float(x3[base + (size_t)r * 512 + 256 + t]));
    __hip_bfloat16 mb = __float2bfloat16(m);
#pragma unroll 4
    for (int r = 0; r < 32; ++r)
        x3[base + (size_t)r * 512 + t] = mb;
}

// ---------------------------------------------------------------------------
// GEMM: C[m,n] = sum_k A[m,k] * W[n,k]  (+ epilogues)
// BM=128, BN=256/512 (full N per block), BK=64, 8 waves (2Mx4N), wave tile 64xWN.
// Staged via global_load_lds(16B) into XOR-swizzled ((row&7)<<4) LDS, dbuf.
// EPI 0: +bias, store bf16 at col offset ocol0 (ld 512)    [h2 -> x3 high half]
// EPI 1: +bias, LayerNorm(BN) * gamma + beta, ReLU, bf16   [h3 -> x3 in-place]
// EPI 2: +bias, max over 32-row groups, store f32          [h4 -> out]
// ---------------------------------------------------------------------------
template <int BN, int EPI>
__global__ __launch_bounds__(512, 2) void gemm_kernel(
    const __hip_bfloat16* A, int lda,
    const __hip_bfloat16* __restrict__ Bw, int ldb, int nkt,
    const float* __restrict__ bias,
    const float* __restrict__ gamma, const float* __restrict__ beta,
    __hip_bfloat16* outB, int ocol0,
    float* __restrict__ outF)
{
    constexpr int BM = 128, BK = 64;
    constexpr int WN = BN / 4;
    constexpr int NI = WN / 16;
    constexpr int MI = 4;
    constexpr int A_ELE = BM * BK;
    constexpr int B_ELE = BN * BK;
    constexpr int BUF = A_ELE + B_ELE;
    constexpr int ACH = A_ELE * 2 / 16 / 512;   // 16B chunks per thread for A
    constexpr int BCH = B_ELE * 2 / 16 / 512;
    __shared__ __hip_bfloat16 smem[2 * BUF];

    const int tid  = threadIdx.x;
    const int wid  = tid >> 6, lane = tid & 63;
    const int wm   = wid >> 2, wn = wid & 3;
    const int lrow = lane & 15, lq = lane >> 4;
    const int m0   = blockIdx.x * BM;

    f32x4 acc[MI][NI] = {};

    auto stage = [&](int buf, int k0) {
        const char* Ab = (const char*)A + ((size_t)m0 * lda + k0) * 2;
        const char* Bb = (const char*)Bw + (size_t)k0 * 2;
        char* sA = (char*)(smem + (size_t)buf * BUF);
        char* sB = sA + A_ELE * 2;
#pragma unroll
        for (int i = 0; i < ACH; ++i) {
            int chunk = i * 512 + tid;
            int Pp = chunk * 16;
            int row = Pp >> 7;
            int kb = (Pp & 127) ^ ((row & 7) << 4);
            const void* g = Ab + (size_t)row * (lda * 2) + kb;
            void* l = sA + (i * 512 + wid * 64) * 16;
            __builtin_amdgcn_global_load_lds((const __attribute__((address_space(1))) void*)g,
                                             (__attribute__((address_space(3))) void*)l, 16, 0, 0);
        }
#pragma unroll
        for (int i = 0; i < BCH; ++i) {
            int chunk = i * 512 + tid;
            int Pp = chunk * 16;
            int n = Pp >> 7;
            int kb = (Pp & 127) ^ ((n & 7) << 4);
            const void* g = Bb + (size_t)n * (ldb * 2) + kb;
            void* l = sB + (i * 512 + wid * 64) * 16;
            __builtin_amdgcn_global_load_lds((const __attribute__((address_space(1))) void*)g,
                                             (__attribute__((address_space(3))) void*)l, 16, 0, 0);
        }
    };

    auto compute = [&](int buf) {
        const char* sA = (const char*)(smem + (size_t)buf * BUF);
        const char* sB = sA + A_ELE * 2;
#pragma unroll
        for (int kk = 0; kk < 2; ++kk) {
            bf16x8 af[MI], bfv[NI];
#pragma unroll
            for (int mi = 0; mi < MI; ++mi) {
                int row = wm * 64 + mi * 16 + lrow;
                int off = row * 128 + ((kk * 64 + lq * 16) ^ ((row & 7) << 4));
                af[mi] = *(const bf16x8*)(sA + off);
            }
#pragma unroll
            for (int ni = 0; ni < NI; ++ni) {
                int n = wn * WN + ni * 16 + lrow;
                int off = n * 128 + ((kk * 64 + lq * 16) ^ ((n & 7) << 4));
                bfv[ni] = *(const bf16x8*)(sB + off);
            }
#pragma unroll
            for (int mi = 0; mi < MI; ++mi)
#pragma unroll
                for (int ni = 0; ni < NI; ++ni)
                    acc[mi][ni] = __builtin_amdgcn_mfma_f32_16x16x32_bf16(af[mi], bfv[ni], acc[mi][ni], 0, 0, 0);
        }
    };

    stage(0, 0);
    __syncthreads();
    int cur = 0;
    for (int kt = 0; kt < nkt; ++kt) {
        if (kt + 1 < nkt) stage(cur ^ 1, (kt + 1) * BK);
        compute(cur);
        __syncthreads();
        cur ^= 1;
    }

    float bv[NI];
#pragma unroll
    for (int ni = 0; ni < NI; ++ni) bv[ni] = bias[wn * WN + ni * 16 + lrow];

    if constexpr (EPI == 0) {
#pragma unroll
        for (int mi = 0; mi < MI; ++mi)
#pragma unroll
            for (int ni = 0; ni < NI; ++ni) {
                int col = ocol0 + wn * WN + ni * 16 + lrow;
#pragma unroll
                for (int j = 0; j < 4; ++j) {
                    int row = wm * 64 + mi * 16 + lq * 4 + j;
                    outB[(size_t)(m0 + row) * 512 + col] = __float2bfloat16(acc[mi][ni][j] + bv[ni]);
                }
            }
    } else if constexpr (EPI == 1) {
        float gv[NI], bev[NI];
#pragma unroll
        for (int ni = 0; ni < NI; ++ni) {
            int col = wn * WN + ni * 16 + lrow;
            gv[ni] = gamma[col]; bev[ni] = beta[col];
        }
#pragma unroll
        for (int mi = 0; mi < MI; ++mi)
#pragma unroll
            for (int ni = 0; ni < NI; ++ni)
#pragma unroll
                for (int j = 0; j < 4; ++j) acc[mi][ni][j] += bv[ni];

        float* rs  = (float*)smem;        // [BM][4] row partial sums
        float* rq  = rs + BM * 4;
        float* rmu = rq + BM * 4;
        float* riv = rmu + BM;
#pragma unroll
        for (int mi = 0; mi < MI; ++mi) {
#pragma unroll
            for (int j = 0; j < 4; ++j) {
                float s = 0.f, q = 0.f;
#pragma unroll
                for (int ni = 0; ni < NI; ++ni) { float v = acc[mi][ni][j]; s += v; q += v * v; }
#pragma unroll
                for (int m = 1; m < 16; m <<= 1) { s += __shfl_xor(s, m, 64); q += __shfl_xor(q, m, 64); }
                if (lrow == 0) {
                    int row = wm * 64 + mi * 16 + lq * 4 + j;
                    rs[row * 4 + wn] = s;
                    rq[row * 4 + wn] = q;
                }
            }
        }
        __syncthreads();
        if (tid < BM) {
            float S = rs[tid * 4 + 0] + rs[tid * 4 + 1] + rs[tid * 4 + 2] + rs[tid * 4 + 3];
            float Q = rq[tid * 4 + 0] + rq[tid * 4 + 1] + rq[tid * 4 + 2] + rq[tid * 4 + 3];
            float mu = S * (1.f / BN);
            float var = Q * (1.f / BN) - mu * mu;
            rmu[tid] = mu;
            riv[tid] = rsqrtf(var + LNEPS);
        }
        __syncthreads();
#pragma unroll
        for (int mi = 0; mi < MI; ++mi)
#pragma unroll
            for (int j = 0; j < 4; ++j) {
                int row = wm * 64 + mi * 16 + lq * 4 + j;
                float mu = rmu[row], iv = riv[row];
#pragma unroll
                for (int ni = 0; ni < NI; ++ni) {
                    float v = (acc[mi][ni][j] - mu) * iv * gv[ni] + bev[ni];
                    v = fmaxf(v, 0.f);
                    outB[(size_t)(m0 + row) * 512 + (wn * WN + ni * 16 + lrow)] = __float2bfloat16(v);
                }
            }
    } else {
#pragma unroll
        for (int grp = 0; grp < 2; ++grp) {
            float mx[NI];
#pragma unroll
            for (int ni = 0; ni < NI; ++ni) {
                float m = -__builtin_inff();
#pragma unroll
                for (int mh = 0; mh < 2; ++mh) {
                    int mi = grp * 2 + mh;
#pragma unroll
                    for (int j = 0; j < 4; ++j) m = fmaxf(m, acc[mi][ni][j] + bv[ni]);
                }
                mx[ni] = m;
            }
#pragma unroll
            for (int ni = 0; ni < NI; ++ni) {
                mx[ni] = fmaxf(mx[ni], __shfl_xor(mx[ni], 16, 64));
                mx[ni] = fmaxf(mx[ni], __shfl_xor(mx[ni], 32, 64));
            }
            if (lq == 0) {
                int grow = (m0 >> 5) + wm * 2 + grp;
#pragma unroll
                for (int ni = 0; ni < NI; ++ni)
                    outF[(size_t)grow * 512 + wn * WN + ni * 16 + lrow] = mx[ni];
            }
        }
    }
}

// ---------------------------------------------------------------------------
extern "C" void kernel_launch(void* const* d_in, const int* in_sizes, int n_in,
                              void* d_out, int out_size, void* d_ws, size_t ws_size,
                              hipStream_t stream)
{
    const float* xyz   = (const float*)d_in[0];
    const float* color = (const float*)d_in[1];
    const float* w1  = (const float*)d_in[2];
    const float* b1  = (const float*)d_in[3];
    const float* g1  = (const float*)d_in[4];
    const float* be1 = (const float*)d_in[5];
    const float* w2  = (const float*)d_in[6];
    const float* b2  = (const float*)d_in[7];
    const float* w3  = (const float*)d_in[8];
    const float* b3  = (const float*)d_in[9];
    const float* g2  = (const float*)d_in[10];
    const float* be2 = (const float*)d_in[11];
    const float* w4  = (const float*)d_in[12];
    const float* b4  = (const float*)d_in[13];
    float* out = (float*)d_out;

    char* ws = (char*)d_ws;
    size_t off = 0;
    auto alloc = [&](size_t bytes) -> void* {
        void* p = ws + off;
        off += (bytes + 255) & ~(size_t)255;
        return p;
    };
    float* centers      = (float*)alloc((size_t)Bn * Gc * 3 * 4);
    float* feats        = (float*)alloc((size_t)Mrows * 6 * 4);
    __hip_bfloat16* w2b = (__hip_bfloat16*)alloc((size_t)256 * 128 * 2);
    __hip_bfloat16* w3b = (__hip_bfloat16*)alloc((size_t)512 * 512 * 2);
    __hip_bfloat16* w4b = (__hip_bfloat16*)alloc((size_t)512 * 512 * 2);
    __hip_bfloat16* h1b = (__hip_bfloat16*)alloc((size_t)Mrows * 128 * 2);
    __hip_bfloat16* x3  = (__hip_bfloat16*)alloc((size_t)Mrows * 512 * 2);
    (void)ws_size; (void)in_sizes; (void)n_in; (void)out_size;

    fps_kernel<<<Bn, 512, 0, stream>>>(xyz, centers);
    knn_feats_kernel<<<Bn * Gc, 256, 0, stream>>>(xyz, color, centers, feats);
    cast_w_kernel<<<1024, 256, 0, stream>>>(w2, w3, w4, w2b, w3b, w4b);
    h1_kernel<<<Mrows / 4, 256, 0, stream>>>(feats, w1, b1, g1, be1, h1b);
    gemm_kernel<256, 0><<<Mrows / 128, 512, 0, stream>>>(h1b, 128, w2b, 128, 2,  b2, nullptr, nullptr, x3, 256, nullptr);
    hgmax_kernel<<<Bn * Gc, 256, 0, stream>>>(x3);
    gemm_kernel<512, 1><<<Mrows / 128, 512, 0, stream>>>(x3, 512, w3b, 512, 8,  b3, g2, be2, x3, 0, nullptr);
    gemm_kernel<512, 2><<<Mrows / 128, 512, 0, stream>>>(x3, 512, w4b, 512, 8,  b4, nullptr, nullptr, nullptr, 0, out);
}

// Round 3
// 1099.785 us; speedup vs baseline: 1.6933x; 1.0332x over previous
//
#include <hip/hip_runtime.h>
#include <hip/hip_bf16.h>
#include <stdint.h>

// Problem constants
constexpr int Bn = 8;              // batches
constexpr int Np = 8192;           // points per batch
constexpr int Gc = 512;            // FPS centers / groups
constexpr int Kn = 32;             // knn neighbors
constexpr int Mrows = Bn * Gc * Kn;  // 131072 encoder rows
constexpr float LNEPS = 1e-5f;

using f32x2  = __attribute__((ext_vector_type(2))) float;
using f32x4  = __attribute__((ext_vector_type(4))) float;
using bf16x8 = __attribute__((ext_vector_type(8))) __bf16;

// ---------------------------------------------------------------------------
// FPS v3: one block per batch, 512 threads, 16 points/thread held as 8x float2
// so the distance chain maps to v_pk_{add,mul}_f32 (2 pts/instr, exact IEEE rn
// per element -> selections identical to reference).
// Inner loop tracks only the f32 running max (v_max). Index is recovered once
// per iteration by a descending equality scan (tie -> smallest index), then a
// single u64 (distbits<<32 | ~idx) feeds the cross-lane/cross-wave argmax.
// Single barrier per iteration via double-buffered per-wave winner slots.
// ---------------------------------------------------------------------------
__global__ __launch_bounds__(512) void fps_kernel(const float* __restrict__ xyz,
                                                  float* __restrict__ centers)
{
    const int b = blockIdx.x;
    const int t = threadIdx.x;
    __shared__ float xs[Np], ys[Np], zs[Np];
    __shared__ unsigned long long red[2][8];
    const float* P = xyz + (size_t)b * Np * 3;
    f32x2 X[8], Y[8], Z[8], MD[8];
#pragma unroll
    for (int i = 0; i < 8; ++i) {
        int p0 = (2 * i) * 512 + t;
        int p1 = (2 * i + 1) * 512 + t;
        float x0 = P[p0 * 3 + 0], y0 = P[p0 * 3 + 1], z0 = P[p0 * 3 + 2];
        float x1 = P[p1 * 3 + 0], y1 = P[p1 * 3 + 1], z1 = P[p1 * 3 + 2];
        X[i] = f32x2{x0, x1}; Y[i] = f32x2{y0, y1}; Z[i] = f32x2{z0, z1};
        xs[p0] = x0; ys[p0] = y0; zs[p0] = z0;
        xs[p1] = x1; ys[p1] = y1; zs[p1] = z1;
        MD[i] = f32x2{__builtin_inff(), __builtin_inff()};
    }
    if (t == 0) {
        centers[(size_t)(b * Gc) * 3 + 0] = P[0];
        centers[(size_t)(b * Gc) * 3 + 1] = P[1];
        centers[(size_t)(b * Gc) * 3 + 2] = P[2];
    }
    __syncthreads();
    int last = 0;
    const int wv = t >> 6, lane = t & 63;
    for (int g = 1; g < Gc; ++g) {
        const float lx = xs[last], ly = ys[last], lz = zs[last];
        const f32x2 cx = {lx, lx}, cy = {ly, ly}, cz = {lz, lz};
        f32x2 bv2 = {-__builtin_inff(), -__builtin_inff()};
#pragma unroll
        for (int i = 0; i < 8; ++i) {
            f32x2 dx = X[i] - cx;
            f32x2 dy = Y[i] - cy;
            f32x2 dz = Z[i] - cz;
            f32x2 d  = (dx * dx + dy * dy) + dz * dz;   // per-element ((x2+y2)+z2), IEEE rn
            f32x2 m  = MD[i];
            m.x = fminf(m.x, d.x); m.y = fminf(m.y, d.y);
            MD[i] = m;
            bv2.x = fmaxf(bv2.x, m.x); bv2.y = fmaxf(bv2.y, m.y);
        }
        const float bv = fmaxf(bv2.x, bv2.y);
        // descending-index equality scan -> smallest matching index survives
        unsigned idx = 0xffffffffu;
#pragma unroll
        for (int i = 7; i >= 0; --i) {
            if (MD[i].y == bv) idx = (unsigned)((2 * i + 1) * 512 + t);
            if (MD[i].x == bv) idx = (unsigned)((2 * i) * 512 + t);
        }
        unsigned long long best =
            ((unsigned long long)__float_as_uint(bv) << 32) | (unsigned long long)(~idx);
#pragma unroll
        for (int m = 1; m < 64; m <<= 1) {
            unsigned long long o = __shfl_xor(best, m, 64);
            best = o > best ? o : best;
        }
        if (lane == 0) red[g & 1][wv] = best;
        __syncthreads();
        unsigned long long w0 = red[g & 1][0];
#pragma unroll
        for (int w = 1; w < 8; ++w) {
            unsigned long long o = red[g & 1][w];
            w0 = o > w0 ? o : w0;
        }
        int wi = (int)(~(unsigned)w0);
        if (t == 0) {
            centers[(size_t)(b * Gc + g) * 3 + 0] = xs[wi];
            centers[(size_t)(b * Gc + g) * 3 + 1] = ys[wi];
            centers[(size_t)(b * Gc + g) * 3 + 2] = zs[wi];
        }
        last = wi;
    }
}

// ---------------------------------------------------------------------------
// KNN + gather + feature build: one block (256 thr) per (b,g).
// d = -2*dot + |c|^2 + |p|^2 exactly as reference; 32x min-extraction,
// tie -> smallest index (stable top_k).
// ---------------------------------------------------------------------------
__global__ __launch_bounds__(256) void knn_feats_kernel(const float* __restrict__ xyz,
                                                        const float* __restrict__ color,
                                                        const float* __restrict__ centers,
                                                        float* __restrict__ feats)
{
    const int bg = blockIdx.x;
    const int b  = bg >> 9;
    const int t  = threadIdx.x;
    __shared__ float rv[4];
    __shared__ int   ri[4], swin, sel[Kn];
    const float cx = centers[(size_t)bg * 3 + 0];
    const float cy = centers[(size_t)bg * 3 + 1];
    const float cz = centers[(size_t)bg * 3 + 2];
    const float cc = __fadd_rn(__fadd_rn(__fmul_rn(cx, cx), __fmul_rn(cy, cy)), __fmul_rn(cz, cz));
    const float* P = xyz + (size_t)b * Np * 3;
    float dr[32];
#pragma unroll
    for (int i = 0; i < 32; ++i) {
        int p = i * 256 + t;
        float px = P[p * 3 + 0], py = P[p * 3 + 1], pz = P[p * 3 + 2];
        float dot = __fadd_rn(__fadd_rn(__fmul_rn(cx, px), __fmul_rn(cy, py)), __fmul_rn(cz, pz));
        float pp  = __fadd_rn(__fadd_rn(__fmul_rn(px, px), __fmul_rn(py, py)), __fmul_rn(pz, pz));
        dr[i] = __fadd_rn(__fadd_rn(__fmul_rn(-2.0f, dot), cc), pp);
    }
    const int lane = t & 63, wvi = t >> 6;
    unsigned excl = 0;
    for (int k = 0; k < Kn; ++k) {
        float bd = __builtin_inff();
        int   bi = 0x7fffffff;
#pragma unroll
        for (int i = 0; i < 32; ++i) {
            float d  = ((excl >> i) & 1u) ? __builtin_inff() : dr[i];
            int  idx = i * 256 + t;
            if (d < bd || (d == bd && idx < bi)) { bd = d; bi = idx; }
        }
#pragma unroll
        for (int m = 1; m < 64; m <<= 1) {
            float od = __shfl_xor(bd, m, 64);
            int   oi = __shfl_xor(bi, m, 64);
            if (od < bd || (od == bd && oi < bi)) { bd = od; bi = oi; }
        }
        if (lane == 0) { rv[wvi] = bd; ri[wvi] = bi; }
        __syncthreads();
        if (t == 0) {
            float wd = rv[0]; int wi = ri[0];
            for (int w = 1; w < 4; ++w)
                if (rv[w] < wd || (rv[w] == wd && ri[w] < wi)) { wd = rv[w]; wi = ri[w]; }
            sel[k] = wi; swin = wi;
        }
        __syncthreads();
        int wi = swin;
        if ((wi & 255) == t) excl |= 1u << (wi >> 8);
    }
    __syncthreads();
    if (t < Kn) {
        int wi = sel[t];
        float px = P[wi * 3 + 0], py = P[wi * 3 + 1], pz = P[wi * 3 + 2];
        const float* C = color + (size_t)b * Np * 3;
        float* F = feats + (size_t)(bg * Kn + t) * 6;
        F[0] = px - cx; F[1] = py - cy; F[2] = pz - cz;
        F[3] = C[wi * 3 + 0]; F[4] = C[wi * 3 + 1]; F[5] = C[wi * 3 + 2];
    }
}

// ---------------------------------------------------------------------------
// Weight cast f32 -> bf16 (w2, w3, w4)
// ---------------------------------------------------------------------------
__global__ void cast_w_kernel(const float* __restrict__ w2, const float* __restrict__ w3,
                              const float* __restrict__ w4,
                              __hip_bfloat16* __restrict__ o2, __hip_bfloat16* __restrict__ o3,
                              __hip_bfloat16* __restrict__ o4)
{
    int i = blockIdx.x * 256 + threadIdx.x;   // grid covers 262144
    if (i < 256 * 128) o2[i] = __float2bfloat16(w2[i]);
    o3[i] = __float2bfloat16(w3[i]);
    o4[i] = __float2bfloat16(w4[i]);
}

// ---------------------------------------------------------------------------
// h1 = relu(LN(feats @ w1^T + b1)); one wave per row (64 lanes x 2 channels)
// ---------------------------------------------------------------------------
__global__ __launch_bounds__(256) void h1_kernel(const float* __restrict__ feats,
                                                 const float* __restrict__ w1,
                                                 const float* __restrict__ b1,
                                                 const float* __restrict__ g1,
                                                 const float* __restrict__ be1,
                                                 __hip_bfloat16* __restrict__ h1)
{
    const int gtid = blockIdx.x * 256 + threadIdx.x;
    const int row  = gtid >> 6;
    const int lane = gtid & 63;
    const float* f = feats + (size_t)row * 6;
    float fr[6];
#pragma unroll
    for (int i = 0; i < 6; ++i) fr[i] = f[i];
    const int c0 = lane * 2;
    float a0 = b1[c0], a1 = b1[c0 + 1];
#pragma unroll
    for (int i = 0; i < 6; ++i) {
        a0 = fmaf(w1[c0 * 6 + i], fr[i], a0);
        a1 = fmaf(w1[(c0 + 1) * 6 + i], fr[i], a1);
    }
    float s = a0 + a1;
#pragma unroll
    for (int m = 1; m < 64; m <<= 1) s += __shfl_xor(s, m, 64);
    float mu = s * (1.f / 128.f);
    float d0 = a0 - mu, d1 = a1 - mu;
    float q = d0 * d0 + d1 * d1;
#pragma unroll
    for (int m = 1; m < 64; m <<= 1) q += __shfl_xor(q, m, 64);
    float iv = rsqrtf(q * (1.f / 128.f) + LNEPS);
    float y0 = fmaxf(0.f, d0 * iv * g1[c0] + be1[c0]);
    float y1 = fmaxf(0.f, d1 * iv * g1[c0 + 1] + be1[c0 + 1]);
    __hip_bfloat16* dst = h1 + (size_t)row * 128 + c0;
    dst[0] = __float2bfloat16(y0);
    dst[1] = __float2bfloat16(y1);
}

// ---------------------------------------------------------------------------
// hg: per-group column max over h2 (x3 cols [256,512)) broadcast into cols [0,256)
// ---------------------------------------------------------------------------
__global__ __launch_bounds__(256) void hgmax_kernel(__hip_bfloat16* x3)
{
    const int grp = blockIdx.x;
    const int t   = threadIdx.x;
    const size_t base = (size_t)grp * 32 * 512;
    float m = -__builtin_inff();
#pragma unroll 4
    for (int r = 0; r < 32; ++r)
        m = fmaxf(m, __bfloat162float(x3[base + (size_t)r * 512 + 256 + t]));
    __hip_bfloat16 mb = __float2bfloat16(m);
#pragma unroll 4
    for (int r = 0; r < 32; ++r)
        x3[base + (size_t)r * 512 + t] = mb;
}

// ---------------------------------------------------------------------------
// GEMM: C[m,n] = sum_k A[m,k] * W[n,k]  (+ epilogues)
// BM=128, BN=256/512 (full N per block), BK=64, 8 waves (2Mx4N), wave tile 64xWN.
// Staged via global_load_lds(16B) into XOR-swizzled ((row&7)<<4) LDS, dbuf.
// EPI 0: +bias, store bf16 at col offset ocol0 (ld 512)    [h2 -> x3 high half]
// EPI 1: +bias, LayerNorm(BN) * gamma + beta, ReLU, bf16   [h3 -> x3 in-place]
// EPI 2: +bias, max over 32-row groups, store f32          [h4 -> out]
// ---------------------------------------------------------------------------
template <int BN, int EPI>
__global__ __launch_bounds__(512, 2) void gemm_kernel(
    const __hip_bfloat16* A, int lda,
    const __hip_bfloat16* __restrict__ Bw, int ldb, int nkt,
    const float* __restrict__ bias,
    const float* __restrict__ gamma, const float* __restrict__ beta,
    __hip_bfloat16* outB, int ocol0,
    float* __restrict__ outF)
{
    constexpr int BM = 128, BK = 64;
    constexpr int WN = BN / 4;
    constexpr int NI = WN / 16;
    constexpr int MI = 4;
    constexpr int A_ELE = BM * BK;
    constexpr int B_ELE = BN * BK;
    constexpr int BUF = A_ELE + B_ELE;
    constexpr int ACH = A_ELE * 2 / 16 / 512;   // 16B chunks per thread for A
    constexpr int BCH = B_ELE * 2 / 16 / 512;
    __shared__ __hip_bfloat16 smem[2 * BUF];

    const int tid  = threadIdx.x;
    const int wid  = tid >> 6, lane = tid & 63;
    const int wm   = wid >> 2, wn = wid & 3;
    const int lrow = lane & 15, lq = lane >> 4;
    const int m0   = blockIdx.x * BM;

    f32x4 acc[MI][NI] = {};

    auto stage = [&](int buf, int k0) {
        const char* Ab = (const char*)A + ((size_t)m0 * lda + k0) * 2;
        const char* Bb = (const char*)Bw + (size_t)k0 * 2;
        char* sA = (char*)(smem + (size_t)buf * BUF);
        char* sB = sA + A_ELE * 2;
#pragma unroll
        for (int i = 0; i < ACH; ++i) {
            int chunk = i * 512 + tid;
            int Pp = chunk * 16;
            int row = Pp >> 7;
            int kb = (Pp & 127) ^ ((row & 7) << 4);
            const void* g = Ab + (size_t)row * (lda * 2) + kb;
            void* l = sA + (i * 512 + wid * 64) * 16;
            __builtin_amdgcn_global_load_lds((const __attribute__((address_space(1))) void*)g,
                                             (__attribute__((address_space(3))) void*)l, 16, 0, 0);
        }
#pragma unroll
        for (int i = 0; i < BCH; ++i) {
            int chunk = i * 512 + tid;
            int Pp = chunk * 16;
            int n = Pp >> 7;
            int kb = (Pp & 127) ^ ((n & 7) << 4);
            const void* g = Bb + (size_t)n * (ldb * 2) + kb;
            void* l = sB + (i * 512 + wid * 64) * 16;
            __builtin_amdgcn_global_load_lds((const __attribute__((address_space(1))) void*)g,
                                             (__attribute__((address_space(3))) void*)l, 16, 0, 0);
        }
    };

    auto compute = [&](int buf) {
        const char* sA = (const char*)(smem + (size_t)buf * BUF);
        const char* sB = sA + A_ELE * 2;
#pragma unroll
        for (int kk = 0; kk < 2; ++kk) {
            bf16x8 af[MI], bfv[NI];
#pragma unroll
            for (int mi = 0; mi < MI; ++mi) {
                int row = wm * 64 + mi * 16 + lrow;
                int off = row * 128 + ((kk * 64 + lq * 16) ^ ((row & 7) << 4));
                af[mi] = *(const bf16x8*)(sA + off);
            }
#pragma unroll
            for (int ni = 0; ni < NI; ++ni) {
                int n = wn * WN + ni * 16 + lrow;
                int off = n * 128 + ((kk * 64 + lq * 16) ^ ((n & 7) << 4));
                bfv[ni] = *(const bf16x8*)(sB + off);
            }
#pragma unroll
            for (int mi = 0; mi < MI; ++mi)
#pragma unroll
                for (int ni = 0; ni < NI; ++ni)
                    acc[mi][ni] = __builtin_amdgcn_mfma_f32_16x16x32_bf16(af[mi], bfv[ni], acc[mi][ni], 0, 0, 0);
        }
    };

    stage(0, 0);
    __syncthreads();
    int cur = 0;
    for (int kt = 0; kt < nkt; ++kt) {
        if (kt + 1 < nkt) stage(cur ^ 1, (kt + 1) * BK);
        compute(cur);
        __syncthreads();
        cur ^= 1;
    }

    float bv[NI];
#pragma unroll
    for (int ni = 0; ni < NI; ++ni) bv[ni] = bias[wn * WN + ni * 16 + lrow];

    if constexpr (EPI == 0) {
#pragma unroll
        for (int mi = 0; mi < MI; ++mi)
#pragma unroll
            for (int ni = 0; ni < NI; ++ni) {
                int col = ocol0 + wn * WN + ni * 16 + lrow;
#pragma unroll
                for (int j = 0; j < 4; ++j) {
                    int row = wm * 64 + mi * 16 + lq * 4 + j;
                    outB[(size_t)(m0 + row) * 512 + col] = __float2bfloat16(acc[mi][ni][j] + bv[ni]);
                }
            }
    } else if constexpr (EPI == 1) {
        float gv[NI], bev[NI];
#pragma unroll
        for (int ni = 0; ni < NI; ++ni) {
            int col = wn * WN + ni * 16 + lrow;
            gv[ni] = gamma[col]; bev[ni] = beta[col];
        }
#pragma unroll
        for (int mi = 0; mi < MI; ++mi)
#pragma unroll
            for (int ni = 0; ni < NI; ++ni)
#pragma unroll
                for (int j = 0; j < 4; ++j) acc[mi][ni][j] += bv[ni];

        float* rs  = (float*)smem;        // [BM][4] row partial sums
        float* rq  = rs + BM * 4;
        float* rmu = rq + BM * 4;
        float* riv = rmu + BM;
#pragma unroll
        for (int mi = 0; mi < MI; ++mi) {
#pragma unroll
            for (int j = 0; j < 4; ++j) {
                float s = 0.f, q = 0.f;
#pragma unroll
                for (int ni = 0; ni < NI; ++ni) { float v = acc[mi][ni][j]; s += v; q += v * v; }
#pragma unroll
                for (int m = 1; m < 16; m <<= 1) { s += __shfl_xor(s, m, 64); q += __shfl_xor(q, m, 64); }
                if (lrow == 0) {
                    int row = wm * 64 + mi * 16 + lq * 4 + j;
                    rs[row * 4 + wn] = s;
                    rq[row * 4 + wn] = q;
                }
            }
        }
        __syncthreads();
        if (tid < BM) {
            float S = rs[tid * 4 + 0] + rs[tid * 4 + 1] + rs[tid * 4 + 2] + rs[tid * 4 + 3];
            float Q = rq[tid * 4 + 0] + rq[tid * 4 + 1] + rq[tid * 4 + 2] + rq[tid * 4 + 3];
            float mu = S * (1.f / BN);
            float var = Q * (1.f / BN) - mu * mu;
            rmu[tid] = mu;
            riv[tid] = rsqrtf(var + LNEPS);
        }
        __syncthreads();
#pragma unroll
        for (int mi = 0; mi < MI; ++mi)
#pragma unroll
            for (int j = 0; j < 4; ++j) {
                int row = wm * 64 + mi * 16 + lq * 4 + j;
                float mu = rmu[row], iv = riv[row];
#pragma unroll
                for (int ni = 0; ni < NI; ++ni) {
                    float v = (acc[mi][ni][j] - mu) * iv * gv[ni] + bev[ni];
                    v = fmaxf(v, 0.f);
                    outB[(size_t)(m0 + row) * 512 + (wn * WN + ni * 16 + lrow)] = __float2bfloat16(v);
                }
            }
    } else {
#pragma unroll
        for (int grp = 0; grp < 2; ++grp) {
            float mx[NI];
#pragma unroll
            for (int ni = 0; ni < NI; ++ni) {
                float m = -__builtin_inff();
#pragma unroll
                for (int mh = 0; mh < 2; ++mh) {
                    int mi = grp * 2 + mh;
#pragma unroll
                    for (int j = 0; j < 4; ++j) m = fmaxf(m, acc[mi][ni][j] + bv[ni]);
                }
                mx[ni] = m;
            }
#pragma unroll
            for (int ni = 0; ni < NI; ++ni) {
                mx[ni] = fmaxf(mx[ni], __shfl_xor(mx[ni], 16, 64));
                mx[ni] = fmaxf(mx[ni], __shfl_xor(mx[ni], 32, 64));
            }
            if (lq == 0) {
                int grow = (m0 >> 5) + wm * 2 + grp;
#pragma unroll
                for (int ni = 0; ni < NI; ++ni)
                    outF[(size_t)grow * 512 + wn * WN + ni * 16 + lrow] = mx[ni];
            }
        }
    }
}

// ---------------------------------------------------------------------------
extern "C" void kernel_launch(void* const* d_in, const int* in_sizes, int n_in,
                              void* d_out, int out_size, void* d_ws, size_t ws_size,
                              hipStream_t stream)
{
    const float* xyz   = (const float*)d_in[0];
    const float* color = (const float*)d_in[1];
    const float* w1  = (const float*)d_in[2];
    const float* b1  = (const float*)d_in[3];
    const float* g1  = (const float*)d_in[4];
    const float* be1 = (const float*)d_in[5];
    const float* w2  = (const float*)d_in[6];
    const float* b2  = (const float*)d_in[7];
    const float* w3  = (const float*)d_in[8];
    const float* b3  = (const float*)d_in[9];
    const float* g2  = (const float*)d_in[10];
    const float* be2 = (const float*)d_in[11];
    const float* w4  = (const float*)d_in[12];
    const float* b4  = (const float*)d_in[13];
    float* out = (float*)d_out;

    char* ws = (char*)d_ws;
    size_t off = 0;
    auto alloc = [&](size_t bytes) -> void* {
        void* p = ws + off;
        off += (bytes + 255) & ~(size_t)255;
        return p;
    };
    float* centers      = (float*)alloc((size_t)Bn * Gc * 3 * 4);
    float* feats        = (float*)alloc((size_t)Mrows * 6 * 4);
    __hip_bfloat16* w2b = (__hip_bfloat16*)alloc((size_t)256 * 128 * 2);
    __hip_bfloat16* w3b = (__hip_bfloat16*)alloc((size_t)512 * 512 * 2);
    __hip_bfloat16* w4b = (__hip_bfloat16*)alloc((size_t)512 * 512 * 2);
    __hip_bfloat16* h1b = (__hip_bfloat16*)alloc((size_t)Mrows * 128 * 2);
    __hip_bfloat16* x3  = (__hip_bfloat16*)alloc((size_t)Mrows * 512 * 2);
    (void)ws_size; (void)in_sizes; (void)n_in; (void)out_size;

    fps_kernel<<<Bn, 512, 0, stream>>>(xyz, centers);
    knn_feats_kernel<<<Bn * Gc, 256, 0, stream>>>(xyz, color, centers, feats);
    cast_w_kernel<<<1024, 256, 0, stream>>>(w2, w3, w4, w2b, w3b, w4b);
    h1_kernel<<<Mrows / 4, 256, 0, stream>>>(feats, w1, b1, g1, be1, h1b);
    gemm_kernel<256, 0><<<Mrows / 128, 512, 0, stream>>>(h1b, 128, w2b, 128, 2,  b2, nullptr, nullptr, x3, 256, nullptr);
    hgmax_kernel<<<Bn * Gc, 256, 0, stream>>>(x3);
    gemm_kernel<512, 1><<<Mrows / 128, 512, 0, stream>>>(x3, 512, w3b, 512, 8,  b3, g2, be2, x3, 0, nullptr);
    gemm_kernel<512, 2><<<Mrows / 128, 512, 0, stream>>>(x3, 512, w4b, 512, 8,  b4, nullptr, nullptr, nullptr, 0, out);
}

// Round 4
// 980.862 us; speedup vs baseline: 1.8986x; 1.1212x over previous
//
#include <hip/hip_runtime.h>
#include <hip/hip_bf16.h>
#include <stdint.h>

// Problem constants
constexpr int Bn = 8;              // batches
constexpr int Np = 8192;           // points per batch
constexpr int Gc = 512;            // FPS centers / groups
constexpr int Kn = 32;             // knn neighbors
constexpr int Mrows = Bn * Gc * Kn;  // 131072 encoder rows
constexpr float LNEPS = 1e-5f;

using f32x2  = __attribute__((ext_vector_type(2))) float;
using f32x4  = __attribute__((ext_vector_type(4))) float;
using bf16x8 = __attribute__((ext_vector_type(8))) __bf16;

#define DEVINL __device__ __forceinline__

// ---- DPP wave64 reductions (canonical GCN sequence; ~12 VALU ops) ----------
// Works in u32 domain: distances are >= 0 so float order == u32 bit order.
DEVINL unsigned wave_red_max_u32(unsigned x) {
    int v = (int)x, t;
    t = __builtin_amdgcn_update_dpp(0, v, 0x111, 0xf, 0xf, false); v = ((unsigned)v > (unsigned)t) ? v : t;
    t = __builtin_amdgcn_update_dpp(0, v, 0x112, 0xf, 0xf, false); v = ((unsigned)v > (unsigned)t) ? v : t;
    t = __builtin_amdgcn_update_dpp(0, v, 0x114, 0xf, 0xf, false); v = ((unsigned)v > (unsigned)t) ? v : t;
    t = __builtin_amdgcn_update_dpp(0, v, 0x118, 0xf, 0xf, false); v = ((unsigned)v > (unsigned)t) ? v : t;
    t = __builtin_amdgcn_update_dpp(0, v, 0x142, 0xa, 0xf, false); v = ((unsigned)v > (unsigned)t) ? v : t;
    t = __builtin_amdgcn_update_dpp(0, v, 0x143, 0xc, 0xf, false); v = ((unsigned)v > (unsigned)t) ? v : t;
    return (unsigned)__builtin_amdgcn_readlane(v, 63);   // full-wave max, uniform
}
DEVINL unsigned wave_red_min_u32(unsigned x) {
    int v = (int)x, t;
    t = __builtin_amdgcn_update_dpp(-1, v, 0x111, 0xf, 0xf, false); v = ((unsigned)v < (unsigned)t) ? v : t;
    t = __builtin_amdgcn_update_dpp(-1, v, 0x112, 0xf, 0xf, false); v = ((unsigned)v < (unsigned)t) ? v : t;
    t = __builtin_amdgcn_update_dpp(-1, v, 0x114, 0xf, 0xf, false); v = ((unsigned)v < (unsigned)t) ? v : t;
    t = __builtin_amdgcn_update_dpp(-1, v, 0x118, 0xf, 0xf, false); v = ((unsigned)v < (unsigned)t) ? v : t;
    t = __builtin_amdgcn_update_dpp(-1, v, 0x142, 0xa, 0xf, false); v = ((unsigned)v < (unsigned)t) ? v : t;
    t = __builtin_amdgcn_update_dpp(-1, v, 0x143, 0xc, 0xf, false); v = ((unsigned)v < (unsigned)t) ? v : t;
    return (unsigned)__builtin_amdgcn_readlane(v, 63);   // full-wave min, uniform
}

// ---------------------------------------------------------------------------
// FPS v4: one block per batch, 512 threads, 16 points/thread (8x float2).
// Exact reference arithmetic preserved (same expression form as v3).
// Serial chain per iter: DPP value-max -> bit-equality scan -> DPP idx-min ->
// lane0 atomicMax(u64 LDS slot, 3-slot rotation) -> 1 barrier ->
// broadcast b64 read -> float4 center read (single ds_read_b128).
// ---------------------------------------------------------------------------
__global__ __launch_bounds__(512) void fps_kernel(const float* __restrict__ xyz,
                                                  float* __restrict__ centers)
{
    const int b = blockIdx.x;
    const int t = threadIdx.x;
    __shared__ f32x4 pts[Np];                    // x,y,z,pad  (131072 B)
    __shared__ unsigned long long sred[3];
    const float* P = xyz + (size_t)b * Np * 3;
    f32x2 X[8], Y[8], Z[8], MD[8];
#pragma unroll
    for (int i = 0; i < 8; ++i) {
        int p0 = (2 * i) * 512 + t;
        int p1 = p0 + 512;
        float x0 = P[p0 * 3 + 0], y0 = P[p0 * 3 + 1], z0 = P[p0 * 3 + 2];
        float x1 = P[p1 * 3 + 0], y1 = P[p1 * 3 + 1], z1 = P[p1 * 3 + 2];
        X[i] = f32x2{x0, x1}; Y[i] = f32x2{y0, y1}; Z[i] = f32x2{z0, z1};
        pts[p0] = f32x4{x0, y0, z0, 0.f};
        pts[p1] = f32x4{x1, y1, z1, 0.f};
        MD[i] = f32x2{__builtin_inff(), __builtin_inff()};
    }
    if (t < 3) sred[t] = 0ull;
    if (t == 0) {
        centers[(size_t)(b * Gc) * 3 + 0] = P[0];
        centers[(size_t)(b * Gc) * 3 + 1] = P[1];
        centers[(size_t)(b * Gc) * 3 + 2] = P[2];
    }
    __syncthreads();
    int last = 0;
    for (int g = 1; g < Gc; ++g) {
        const f32x4 c4 = pts[last];
        const f32x2 cx = {c4.x, c4.x}, cy = {c4.y, c4.y}, cz = {c4.z, c4.z};
        f32x2 bv2 = {0.f, 0.f};                  // md >= 0, so 0 is a safe identity
#pragma unroll
        for (int i = 0; i < 8; ++i) {
            f32x2 dx = X[i] - cx;
            f32x2 dy = Y[i] - cy;
            f32x2 dz = Z[i] - cz;
            f32x2 d  = (dx * dx + dy * dy) + dz * dz;   // same expr form as v3 (passed)
            f32x2 m  = MD[i];
            m.x = fminf(m.x, d.x); m.y = fminf(m.y, d.y);
            MD[i] = m;
            bv2.x = fmaxf(bv2.x, m.x); bv2.y = fmaxf(bv2.y, m.y);
        }
        const float bv = fmaxf(bv2.x, bv2.y);
        // wave-level value max (u32 bit domain valid for non-negative floats)
        const unsigned wmax = wave_red_max_u32(__float_as_uint(bv));
        // smallest local index matching the wave max (descending scan)
        unsigned idx = 0xffffffffu;
#pragma unroll
        for (int i = 7; i >= 0; --i) {
            if (__float_as_uint(MD[i].y) == wmax) idx = (unsigned)((2 * i + 1) * 512 + t);
            if (__float_as_uint(MD[i].x) == wmax) idx = (unsigned)((2 * i) * 512 + t);
        }
        const unsigned widx = wave_red_min_u32(idx);
        // cross-wave combine: one u64 atomicMax per wave into rotating slot
        if ((t & 63) == 0) {
            unsigned long long pack =
                ((unsigned long long)wmax << 32) | (unsigned long long)(~widx);
            atomicMax(&sred[g % 3], pack);
        }
        if (t == 1) sred[(g + 1) % 3] = 0ull;    // zero next slot (distance-3 reuse: safe)
        __syncthreads();
        const unsigned long long w = sred[g % 3];
        const int wi = (int)(~(unsigned)w);
        if (t == 0) {
            f32x4 c = pts[wi];
            centers[(size_t)(b * Gc + g) * 3 + 0] = c.x;
            centers[(size_t)(b * Gc + g) * 3 + 1] = c.y;
            centers[(size_t)(b * Gc + g) * 3 + 2] = c.z;
        }
        last = wi;
    }
}

// ---------------------------------------------------------------------------
// KNN + gather + feature build: one block (256 thr) per (b,g).
// d = -2*dot + |c|^2 + |p|^2 exactly as reference; 32x min-extraction,
// tie -> smallest index (stable top_k).
// ---------------------------------------------------------------------------
__global__ __launch_bounds__(256) void knn_feats_kernel(const float* __restrict__ xyz,
                                                        const float* __restrict__ color,
                                                        const float* __restrict__ centers,
                                                        float* __restrict__ feats)
{
    const int bg = blockIdx.x;
    const int b  = bg >> 9;
    const int t  = threadIdx.x;
    __shared__ float rv[4];
    __shared__ int   ri[4], swin, sel[Kn];
    const float cx = centers[(size_t)bg * 3 + 0];
    const float cy = centers[(size_t)bg * 3 + 1];
    const float cz = centers[(size_t)bg * 3 + 2];
    const float cc = __fadd_rn(__fadd_rn(__fmul_rn(cx, cx), __fmul_rn(cy, cy)), __fmul_rn(cz, cz));
    const float* P = xyz + (size_t)b * Np * 3;
    float dr[32];
#pragma unroll
    for (int i = 0; i < 32; ++i) {
        int p = i * 256 + t;
        float px = P[p * 3 + 0], py = P[p * 3 + 1], pz = P[p * 3 + 2];
        float dot = __fadd_rn(__fadd_rn(__fmul_rn(cx, px), __fmul_rn(cy, py)), __fmul_rn(cz, pz));
        float pp  = __fadd_rn(__fadd_rn(__fmul_rn(px, px), __fmul_rn(py, py)), __fmul_rn(pz, pz));
        dr[i] = __fadd_rn(__fadd_rn(__fmul_rn(-2.0f, dot), cc), pp);
    }
    const int lane = t & 63, wvi = t >> 6;
    unsigned excl = 0;
    for (int k = 0; k < Kn; ++k) {
        float bd = __builtin_inff();
        int   bi = 0x7fffffff;
#pragma unroll
        for (int i = 0; i < 32; ++i) {
            float d  = ((excl >> i) & 1u) ? __builtin_inff() : dr[i];
            int  idx = i * 256 + t;
            if (d < bd || (d == bd && idx < bi)) { bd = d; bi = idx; }
        }
#pragma unroll
        for (int m = 1; m < 64; m <<= 1) {
            float od = __shfl_xor(bd, m, 64);
            int   oi = __shfl_xor(bi, m, 64);
            if (od < bd || (od == bd && oi < bi)) { bd = od; bi = oi; }
        }
        if (lane == 0) { rv[wvi] = bd; ri[wvi] = bi; }
        __syncthreads();
        if (t == 0) {
            float wd = rv[0]; int wi = ri[0];
            for (int w = 1; w < 4; ++w)
                if (rv[w] < wd || (rv[w] == wd && ri[w] < wi)) { wd = rv[w]; wi = ri[w]; }
            sel[k] = wi; swin = wi;
        }
        __syncthreads();
        int wi = swin;
        if ((wi & 255) == t) excl |= 1u << (wi >> 8);
    }
    __syncthreads();
    if (t < Kn) {
        int wi = sel[t];
        float px = P[wi * 3 + 0], py = P[wi * 3 + 1], pz = P[wi * 3 + 2];
        const float* C = color + (size_t)b * Np * 3;
        float* F = feats + (size_t)(bg * Kn + t) * 6;
        F[0] = px - cx; F[1] = py - cy; F[2] = pz - cz;
        F[3] = C[wi * 3 + 0]; F[4] = C[wi * 3 + 1]; F[5] = C[wi * 3 + 2];
    }
}

// ---------------------------------------------------------------------------
// Weight cast f32 -> bf16 (w2, w3, w4)
// ---------------------------------------------------------------------------
__global__ void cast_w_kernel(const float* __restrict__ w2, const float* __restrict__ w3,
                              const float* __restrict__ w4,
                              __hip_bfloat16* __restrict__ o2, __hip_bfloat16* __restrict__ o3,
                              __hip_bfloat16* __restrict__ o4)
{
    int i = blockIdx.x * 256 + threadIdx.x;   // grid covers 262144
    if (i < 256 * 128) o2[i] = __float2bfloat16(w2[i]);
    o3[i] = __float2bfloat16(w3[i]);
    o4[i] = __float2bfloat16(w4[i]);
}

// ---------------------------------------------------------------------------
// h1 = relu(LN(feats @ w1^T + b1)); one wave per row (64 lanes x 2 channels)
// ---------------------------------------------------------------------------
__global__ __launch_bounds__(256) void h1_kernel(const float* __restrict__ feats,
                                                 const float* __restrict__ w1,
                                                 const float* __restrict__ b1,
                                                 const float* __restrict__ g1,
                                                 const float* __restrict__ be1,
                                                 __hip_bfloat16* __restrict__ h1)
{
    const int gtid = blockIdx.x * 256 + threadIdx.x;
    const int row  = gtid >> 6;
    const int lane = gtid & 63;
    const float* f = feats + (size_t)row * 6;
    float fr[6];
#pragma unroll
    for (int i = 0; i < 6; ++i) fr[i] = f[i];
    const int c0 = lane * 2;
    float a0 = b1[c0], a1 = b1[c0 + 1];
#pragma unroll
    for (int i = 0; i < 6; ++i) {
        a0 = fmaf(w1[c0 * 6 + i], fr[i], a0);
        a1 = fmaf(w1[(c0 + 1) * 6 + i], fr[i], a1);
    }
    float s = a0 + a1;
#pragma unroll
    for (int m = 1; m < 64; m <<= 1) s += __shfl_xor(s, m, 64);
    float mu = s * (1.f / 128.f);
    float d0 = a0 - mu, d1 = a1 - mu;
    float q = d0 * d0 + d1 * d1;
#pragma unroll
    for (int m = 1; m < 64; m <<= 1) q += __shfl_xor(q, m, 64);
    float iv = rsqrtf(q * (1.f / 128.f) + LNEPS);
    float y0 = fmaxf(0.f, d0 * iv * g1[c0] + be1[c0]);
    float y1 = fmaxf(0.f, d1 * iv * g1[c0 + 1] + be1[c0 + 1]);
    __hip_bfloat16* dst = h1 + (size_t)row * 128 + c0;
    dst[0] = __float2bfloat16(y0);
    dst[1] = __float2bfloat16(y1);
}

// ---------------------------------------------------------------------------
// hg: per-group column max over h2 (x3 cols [256,512)) broadcast into cols [0,256)
// ---------------------------------------------------------------------------
__global__ __launch_bounds__(256) void hgmax_kernel(__hip_bfloat16* x3)
{
    const int grp = blockIdx.x;
    const int t   = threadIdx.x;
    const size_t base = (size_t)grp * 32 * 512;
    float m = -__builtin_inff();
#pragma unroll 4
    for (int r = 0; r < 32; ++r)
        m = fmaxf(m, __bfloat162float(x3[base + (size_t)r * 512 + 256 + t]));
    __hip_bfloat16 mb = __float2bfloat16(m);
#pragma unroll 4
    for (int r = 0; r < 32; ++r)
        x3[base + (size_t)r * 512 + t] = mb;
}

// ---------------------------------------------------------------------------
// GEMM: C[m,n] = sum_k A[m,k] * W[n,k]  (+ epilogues)
// BM=128, BN=256/512 (full N per block), BK=64, 8 waves (2Mx4N), wave tile 64xWN.
// Staged via global_load_lds(16B) into XOR-swizzled ((row&7)<<4) LDS, dbuf.
// EPI 0: +bias, store bf16 at col offset ocol0 (ld 512)    [h2 -> x3 high half]
// EPI 1: +bias, LayerNorm(BN) * gamma + beta, ReLU, bf16   [h3 -> x3 in-place]
// EPI 2: +bias, max over 32-row groups, store f32          [h4 -> out]
// ---------------------------------------------------------------------------
template <int BN, int EPI>
__global__ __launch_bounds__(512, 2) void gemm_kernel(
    const __hip_bfloat16* A, int lda,
    const __hip_bfloat16* __restrict__ Bw, int ldb, int nkt,
    const float* __restrict__ bias,
    const float* __restrict__ gamma, const float* __restrict__ beta,
    __hip_bfloat16* outB, int ocol0,
    float* __restrict__ outF)
{
    constexpr int BM = 128, BK = 64;
    constexpr int WN = BN / 4;
    constexpr int NI = WN / 16;
    constexpr int MI = 4;
    constexpr int A_ELE = BM * BK;
    constexpr int B_ELE = BN * BK;
    constexpr int BUF = A_ELE + B_ELE;
    constexpr int ACH = A_ELE * 2 / 16 / 512;   // 16B chunks per thread for A
    constexpr int BCH = B_ELE * 2 / 16 / 512;
    __shared__ __hip_bfloat16 smem[2 * BUF];

    const int tid  = threadIdx.x;
    const int wid  = tid >> 6, lane = tid & 63;
    const int wm   = wid >> 2, wn = wid & 3;
    const int lrow = lane & 15, lq = lane >> 4;
    const int m0   = blockIdx.x * BM;

    f32x4 acc[MI][NI] = {};

    auto stage = [&](int buf, int k0) {
        const char* Ab = (const char*)A + ((size_t)m0 * lda + k0) * 2;
        const char* Bb = (const char*)Bw + (size_t)k0 * 2;
        char* sA = (char*)(smem + (size_t)buf * BUF);
        char* sB = sA + A_ELE * 2;
#pragma unroll
        for (int i = 0; i < ACH; ++i) {
            int chunk = i * 512 + tid;
            int Pp = chunk * 16;
            int row = Pp >> 7;
            int kb = (Pp & 127) ^ ((row & 7) << 4);
            const void* g = Ab + (size_t)row * (lda * 2) + kb;
            void* l = sA + (i * 512 + wid * 64) * 16;
            __builtin_amdgcn_global_load_lds((const __attribute__((address_space(1))) void*)g,
                                             (__attribute__((address_space(3))) void*)l, 16, 0, 0);
        }
#pragma unroll
        for (int i = 0; i < BCH; ++i) {
            int chunk = i * 512 + tid;
            int Pp = chunk * 16;
            int n = Pp >> 7;
            int kb = (Pp & 127) ^ ((n & 7) << 4);
            const void* g = Bb + (size_t)n * (ldb * 2) + kb;
            void* l = sB + (i * 512 + wid * 64) * 16;
            __builtin_amdgcn_global_load_lds((const __attribute__((address_space(1))) void*)g,
                                             (__attribute__((address_space(3))) void*)l, 16, 0, 0);
        }
    };

    auto compute = [&](int buf) {
        const char* sA = (const char*)(smem + (size_t)buf * BUF);
        const char* sB = sA + A_ELE * 2;
#pragma unroll
        for (int kk = 0; kk < 2; ++kk) {
            bf16x8 af[MI], bfv[NI];
#pragma unroll
            for (int mi = 0; mi < MI; ++mi) {
                int row = wm * 64 + mi * 16 + lrow;
                int off = row * 128 + ((kk * 64 + lq * 16) ^ ((row & 7) << 4));
                af[mi] = *(const bf16x8*)(sA + off);
            }
#pragma unroll
            for (int ni = 0; ni < NI; ++ni) {
                int n = wn * WN + ni * 16 + lrow;
                int off = n * 128 + ((kk * 64 + lq * 16) ^ ((n & 7) << 4));
                bfv[ni] = *(const bf16x8*)(sB + off);
            }
#pragma unroll
            for (int mi = 0; mi < MI; ++mi)
#pragma unroll
                for (int ni = 0; ni < NI; ++ni)
                    acc[mi][ni] = __builtin_amdgcn_mfma_f32_16x16x32_bf16(af[mi], bfv[ni], acc[mi][ni], 0, 0, 0);
        }
    };

    stage(0, 0);
    __syncthreads();
    int cur = 0;
    for (int kt = 0; kt < nkt; ++kt) {
        if (kt + 1 < nkt) stage(cur ^ 1, (kt + 1) * BK);
        compute(cur);
        __syncthreads();
        cur ^= 1;
    }

    float bv[NI];
#pragma unroll
    for (int ni = 0; ni < NI; ++ni) bv[ni] = bias[wn * WN + ni * 16 + lrow];

    if constexpr (EPI == 0) {
#pragma unroll
        for (int mi = 0; mi < MI; ++mi)
#pragma unroll
            for (int ni = 0; ni < NI; ++ni) {
                int col = ocol0 + wn * WN + ni * 16 + lrow;
#pragma unroll
                for (int j = 0; j < 4; ++j) {
                    int row = wm * 64 + mi * 16 + lq * 4 + j;
                    outB[(size_t)(m0 + row) * 512 + col] = __float2bfloat16(acc[mi][ni][j] + bv[ni]);
                }
            }
    } else if constexpr (EPI == 1) {
        float gv[NI], bev[NI];
#pragma unroll
        for (int ni = 0; ni < NI; ++ni) {
            int col = wn * WN + ni * 16 + lrow;
            gv[ni] = gamma[col]; bev[ni] = beta[col];
        }
#pragma unroll
        for (int mi = 0; mi < MI; ++mi)
#pragma unroll
            for (int ni = 0; ni < NI; ++ni)
#pragma unroll
                for (int j = 0; j < 4; ++j) acc[mi][ni][j] += bv[ni];

        float* rs  = (float*)smem;        // [BM][4] row partial sums
        float* rq  = rs + BM * 4;
        float* rmu = rq + BM * 4;
        float* riv = rmu + BM;
#pragma unroll
        for (int mi = 0; mi < MI; ++mi) {
#pragma unroll
            for (int j = 0; j < 4; ++j) {
                float s = 0.f, q = 0.f;
#pragma unroll
                for (int ni = 0; ni < NI; ++ni) { float v = acc[mi][ni][j]; s += v; q += v * v; }
#pragma unroll
                for (int m = 1; m < 16; m <<= 1) { s += __shfl_xor(s, m, 64); q += __shfl_xor(q, m, 64); }
                if (lrow == 0) {
                    int row = wm * 64 + mi * 16 + lq * 4 + j;
                    rs[row * 4 + wn] = s;
                    rq[row * 4 + wn] = q;
                }
            }
        }
        __syncthreads();
        if (tid < BM) {
            float S = rs[tid * 4 + 0] + rs[tid * 4 + 1] + rs[tid * 4 + 2] + rs[tid * 4 + 3];
            float Q = rq[tid * 4 + 0] + rq[tid * 4 + 1] + rq[tid * 4 + 2] + rq[tid * 4 + 3];
            float mu = S * (1.f / BN);
            float var = Q * (1.f / BN) - mu * mu;
            rmu[tid] = mu;
            riv[tid] = rsqrtf(var + LNEPS);
        }
        __syncthreads();
#pragma unroll
        for (int mi = 0; mi < MI; ++mi)
#pragma unroll
            for (int j = 0; j < 4; ++j) {
                int row = wm * 64 + mi * 16 + lq * 4 + j;
                float mu = rmu[row], iv = riv[row];
#pragma unroll
                for (int ni = 0; ni < NI; ++ni) {
                    float v = (acc[mi][ni][j] - mu) * iv * gv[ni] + bev[ni];
                    v = fmaxf(v, 0.f);
                    outB[(size_t)(m0 + row) * 512 + (wn * WN + ni * 16 + lrow)] = __float2bfloat16(v);
                }
            }
    } else {
#pragma unroll
        for (int grp = 0; grp < 2; ++grp) {
            float mx[NI];
#pragma unroll
            for (int ni = 0; ni < NI; ++ni) {
                float m = -__builtin_inff();
#pragma unroll
                for (int mh = 0; mh < 2; ++mh) {
                    int mi = grp * 2 + mh;
#pragma unroll
                    for (int j = 0; j < 4; ++j) m = fmaxf(m, acc[mi][ni][j] + bv[ni]);
                }
                mx[ni] = m;
            }
#pragma unroll
            for (int ni = 0; ni < NI; ++ni) {
                mx[ni] = fmaxf(mx[ni], __shfl_xor(mx[ni], 16, 64));
                mx[ni] = fmaxf(mx[ni], __shfl_xor(mx[ni], 32, 64));
            }
            if (lq == 0) {
                int grow = (m0 >> 5) + wm * 2 + grp;
#pragma unroll
                for (int ni = 0; ni < NI; ++ni)
                    outF[(size_t)grow * 512 + wn * WN + ni * 16 + lrow] = mx[ni];
            }
        }
    }
}

// ---------------------------------------------------------------------------
extern "C" void kernel_launch(void* const* d_in, const int* in_sizes, int n_in,
                              void* d_out, int out_size, void* d_ws, size_t ws_size,
                              hipStream_t stream)
{
    const float* xyz   = (const float*)d_in[0];
    const float* color = (const float*)d_in[1];
    const float* w1  = (const float*)d_in[2];
    const float* b1  = (const float*)d_in[3];
    const float* g1  = (const float*)d_in[4];
    const float* be1 = (const float*)d_in[5];
    const float* w2  = (const float*)d_in[6];
    const float* b2  = (const float*)d_in[7];
    const float* w3  = (const float*)d_in[8];
    const float* b3  = (const float*)d_in[9];
    const float* g2  = (const float*)d_in[10];
    const float* be2 = (const float*)d_in[11];
    const float* w4  = (const float*)d_in[12];
    const float* b4  = (const float*)d_in[13];
    float* out = (float*)d_out;

    char* ws = (char*)d_ws;
    size_t off = 0;
    auto alloc = [&](size_t bytes) -> void* {
        void* p = ws + off;
        off += (bytes + 255) & ~(size_t)255;
        return p;
    };
    float* centers      = (float*)alloc((size_t)Bn * Gc * 3 * 4);
    float* feats        = (float*)alloc((size_t)Mrows * 6 * 4);
    __hip_bfloat16* w2b = (__hip_bfloat16*)alloc((size_t)256 * 128 * 2);
    __hip_bfloat16* w3b = (__hip_bfloat16*)alloc((size_t)512 * 512 * 2);
    __hip_bfloat16* w4b = (__hip_bfloat16*)alloc((size_t)512 * 512 * 2);
    __hip_bfloat16* h1b = (__hip_bfloat16*)alloc((size_t)Mrows * 128 * 2);
    __hip_bfloat16* x3  = (__hip_bfloat16*)alloc((size_t)Mrows * 512 * 2);
    (void)ws_size; (void)in_sizes; (void)n_in; (void)out_size;

    fps_kernel<<<Bn, 512, 0, stream>>>(xyz, centers);
    knn_feats_kernel<<<Bn * Gc, 256, 0, stream>>>(xyz, color, centers, feats);
    cast_w_kernel<<<1024, 256, 0, stream>>>(w2, w3, w4, w2b, w3b, w4b);
    h1_kernel<<<Mrows / 4, 256, 0, stream>>>(feats, w1, b1, g1, be1, h1b);
    gemm_kernel<256, 0><<<Mrows / 128, 512, 0, stream>>>(h1b, 128, w2b, 128, 2,  b2, nullptr, nullptr, x3, 256, nullptr);
    hgmax_kernel<<<Bn * Gc, 256, 0, stream>>>(x3);
    gemm_kernel<512, 1><<<Mrows / 128, 512, 0, stream>>>(x3, 512, w3b, 512, 8,  b3, g2, be2, x3, 0, nullptr);
    gemm_kernel<512, 2><<<Mrows / 128, 512, 0, stream>>>(x3, 512, w4b, 512, 8,  b4, nullptr, nullptr, nullptr, 0, out);
}